// Round 11
// baseline (211.892 us; speedup 1.0000x reference)
//
#include <hip/hip_runtime.h>
#include <hip/hip_bf16.h>

#define N_NODES 50000
#define N_EDGES 800000
#define N_IN    256
#define N_H     64
#define NB      125    // buckets per graph
#define RPB     400    // rows per bucket (NB*RPB == N_NODES)
#define BCAP    8192   // bucket capacity (mean 6400)
#define EPT     8      // edges per thread in k_bin
#define BIN_BLK 2048   // edges per k_bin block
#define GSTRIDE 256    // u16 per WTg row (unpadded; B goes to registers)
#define ASTRIDE 264    // u16 per A-LDS row (256 + 8 pad)
#define NTILES  1563   // ceil(N_NODES/32)
#define GEMMX   192    // persistent blocks per stream

typedef short short8 __attribute__((ext_vector_type(8)));
typedef float f32x4  __attribute__((ext_vector_type(4)));

__device__ inline short f2bf(float f) {
    __bf16 h = (__bf16)f;
    return (short)__builtin_bit_cast(unsigned short, h);
}
__device__ inline float bflo(unsigned int q) { return __uint_as_float(q << 16); }
__device__ inline float bfhi(unsigned int q) { return __uint_as_float(q & 0xFFFF0000u); }

// ---------------- phase 1: bin edges by row range ----------------

__global__ __launch_bounds__(256) void k_bin(
    const int* __restrict__ adj_rows, const int* __restrict__ adj_cols,
    const float* __restrict__ adj_w,
    const int* __restrict__ diff_rows, const int* __restrict__ diff_cols,
    const float* __restrict__ diff_w,
    int* __restrict__ gcnt, int2* __restrict__ bin) {

    int g = blockIdx.y;
    const int*   rows = g ? diff_rows : adj_rows;
    const int*   cols = g ? diff_cols : adj_cols;
    const float* ww   = g ? diff_w    : adj_w;
    int base_e = blockIdx.x * BIN_BLK;
    int t = threadIdx.x;

    __shared__ int lcnt[NB];
    __shared__ int lbase[NB];
    for (int i = t; i < NB; i += 256) lcnt[i] = 0;
    __syncthreads();

    int lpos[EPT];
    int bkt[EPT];
    #pragma unroll
    for (int e = 0; e < EPT; ++e) {
        int idx = base_e + e * 256 + t;
        if (idx < N_EDGES) {
            int r = rows[idx];
            int b = r / RPB;
            bkt[e] = b;
            lpos[e] = atomicAdd(&lcnt[b], 1);
        } else bkt[e] = -1;
    }
    __syncthreads();
    for (int i = t; i < NB; i += 256) lbase[i] = atomicAdd(&gcnt[g * NB + i], lcnt[i]);
    __syncthreads();

    #pragma unroll
    for (int e = 0; e < EPT; ++e) {
        int idx = base_e + e * 256 + t;
        if (idx < N_EDGES) {
            unsigned int r = (unsigned int)rows[idx];
            unsigned int c = (unsigned int)cols[idx];
            int b = bkt[e];
            int2 m;
            m.x = (int)((r << 16) | c);
            m.y = __float_as_int(ww[idx]);
            bin[((size_t)(g * NB + b)) * BCAP + lbase[b] + lpos[e]] = m;
        }
    }
}

// ---------------- phase 2: per-bucket CSR build ----------------

__global__ __launch_bounds__(256) void k_build(
    const int* __restrict__ gcnt, const int2* __restrict__ bin,
    int2* __restrict__ csr, int* __restrict__ row_ptr) {

    int g = blockIdx.y, b = blockIdx.x, t = threadIdx.x;
    __shared__ int hist[512];
    __shared__ int s2[256];
    __shared__ int sbase;

    for (int i = t; i < 512; i += 256) hist[i] = 0;
    __syncthreads();

    int cnt = gcnt[g * NB + b];
    const int2* be = bin + ((size_t)(g * NB + b)) * BCAP;
    int r0 = b * RPB;

    for (int i = t; i < cnt; i += 256) {
        unsigned int rc = (unsigned int)be[i].x;
        atomicAdd(&hist[(rc >> 16) - r0], 1);
    }
    __syncthreads();

    if (t == 0) {
        int s = 0;
        for (int i = 0; i < b; ++i) s += gcnt[g * NB + i];
        sbase = s;
    }

    int v0 = hist[2 * t], v1 = hist[2 * t + 1];
    int local = v0 + v1;
    s2[t] = local;
    __syncthreads();
    for (int off = 1; off < 256; off <<= 1) {
        int v = (t >= off) ? s2[t - off] : 0;
        __syncthreads();
        s2[t] += v;
        __syncthreads();
    }
    int e0 = sbase + (s2[t] - local);
    int e1 = e0 + v0;

    int* rp = row_ptr + g * (N_NODES + 1);
    if (2 * t < RPB)     rp[r0 + 2 * t]     = e0;
    if (2 * t + 1 < RPB) rp[r0 + 2 * t + 1] = e1;
    __syncthreads();
    hist[2 * t] = e0;
    hist[2 * t + 1] = e1;
    __syncthreads();

    int2* cg = csr + (size_t)g * N_EDGES;
    for (int i = t; i < cnt; i += 256) {
        int2 m = be[i];
        unsigned int rc = (unsigned int)m.x;
        int lr = (int)(rc >> 16) - r0;
        int pos = atomicAdd(&hist[lr], 1);
        int2 o;
        o.x = (int)(rc & 0xFFFFu);
        o.y = m.y;
        cg[pos] = o;
    }
    if (b == NB - 1 && t == 0) rp[N_NODES] = N_EDGES;
}

// ---------------- prep: bf16 W^T tables in global ----------------

__global__ __launch_bounds__(256) void k_wt(const float* __restrict__ W1,
                                            const float* __restrict__ W2,
                                            unsigned short* __restrict__ WTg) {
    int g = blockIdx.x;
    const float* W = g ? W2 : W1;
    unsigned short* o = WTg + (size_t)g * 64 * GSTRIDE;
    for (int i = threadIdx.x; i < N_IN * N_H; i += 256) {
        int k = i >> 6, c = i & 63;
        o[c * GSTRIDE + k] = (unsigned short)f2bf(W[i]);
    }
}

// ---------------- GEMM: persistent blocks, PING-PONG double-buffered staging ----------------
// grid (GEMMX, 4); blockIdx.y = (g,s) stream. Block loops tiles of 32 rows.
// vA/vB alternate roles by iteration parity -> no register copy -> the allocator
// cannot coalesce the prefetch into the live buffer (r10 failure: VGPR=72).

#define LOADV(dst, tl)                                                  \
    {                                                                   \
        int base_ = (tl) * 32 + wid;                                    \
        _Pragma("unroll")                                               \
        for (int j = 0; j < 8; ++j) {                                   \
            int grow_ = base_ + 4 * j;                                  \
            if (grow_ >= N_NODES) grow_ = N_NODES - 1;                  \
            dst[j] = ((const float4*)(X + (size_t)grow_ * N_IN))[col4]; \
        }                                                               \
    }

#define STAGEV(src)                                                    \
    {                                                                   \
        _Pragma("unroll")                                               \
        for (int j = 0; j < 8; ++j) {                                   \
            int row_ = wid + 4 * j;                                     \
            ushort4 c_;                                                 \
            c_.x = (unsigned short)f2bf(src[j].x);                      \
            c_.y = (unsigned short)f2bf(src[j].y);                      \
            c_.z = (unsigned short)f2bf(src[j].z);                      \
            c_.w = (unsigned short)f2bf(src[j].w);                      \
            *reinterpret_cast<ushort4*>(&A[row_ * ASTRIDE + col4 * 4]) = c_; \
        }                                                               \
    }

__global__ __launch_bounds__(256, 3) void k_gemm(
    const float* __restrict__ X0, const float* __restrict__ X1,
    const float* __restrict__ X2, const float* __restrict__ X3,
    const unsigned short* __restrict__ WTg,
    unsigned short* __restrict__ Tadj, unsigned short* __restrict__ Tdiff) {

    int gy = blockIdx.y;
    int g = gy >> 1, s = gy & 1;
    const float* X = g ? (s ? X3 : X1) : (s ? X2 : X0);
    unsigned short* T = g ? Tdiff : Tadj;
    const unsigned short* WB = WTg + (size_t)g * 64 * GSTRIDE;
    int coloff = s * 64;

    int t    = threadIdx.x;
    int wid  = t >> 6;
    int lane = t & 63;
    int l15  = lane & 15;
    int kg   = lane >> 4;
    int col4 = t & 63;          // staging: thread covers rows wid+4j, float4-chunk col4

    __shared__ __align__(16) unsigned short A[32 * ASTRIDE];   // 16896 B

    // B fragments once per block (L2-hot 32 KB table)
    int ctbase = (wid >> 1) * 2;
    short8 bfr[2][8];
    #pragma unroll
    for (int c2 = 0; c2 < 2; ++c2) {
        int ct = ctbase + c2;
        #pragma unroll
        for (int kt = 0; kt < 8; ++kt) {
            bfr[c2][kt] = *reinterpret_cast<const short8*>(
                WB + ((ct * 16 + l15) * GSTRIDE + kt * 32 + kg * 8));
        }
    }

    int rt = wid & 1;
    int tile = blockIdx.x;
    int par = 0;

    float4 vA[8], vB[8];
    LOADV(vA, tile);

    while (tile < NTILES) {
        int nxt = tile + GEMMX;
        if (par == 0) {
            if (nxt < NTILES) LOADV(vB, nxt);
            __builtin_amdgcn_sched_barrier(0);   // prefetch issued HERE, stays here
            STAGEV(vA);
        } else {
            if (nxt < NTILES) LOADV(vA, nxt);
            __builtin_amdgcn_sched_barrier(0);
            STAGEV(vB);
        }
        __syncthreads();

        f32x4 acc[2];
        acc[0] = (f32x4){0.f, 0.f, 0.f, 0.f};
        acc[1] = (f32x4){0.f, 0.f, 0.f, 0.f};
        #pragma unroll
        for (int kt = 0; kt < 8; ++kt) {
            short8 af = *reinterpret_cast<const short8*>(
                &A[(rt * 16 + l15) * ASTRIDE + kt * 32 + kg * 8]);
            acc[0] = __builtin_amdgcn_mfma_f32_16x16x32_bf16(af, bfr[0][kt], acc[0], 0, 0, 0);
            acc[1] = __builtin_amdgcn_mfma_f32_16x16x32_bf16(af, bfr[1][kt], acc[1], 0, 0, 0);
        }

        int rb0 = tile * 32;
        #pragma unroll
        for (int c2 = 0; c2 < 2; ++c2) {
            int col = coloff + (ctbase + c2) * 16 + l15;
            #pragma unroll
            for (int r = 0; r < 4; ++r) {
                int row = rb0 + rt * 16 + kg * 4 + r;
                if (row < N_NODES)
                    T[(size_t)row * 128 + col] = (unsigned short)f2bf(acc[c2][r]);
            }
        }
        __syncthreads();     // A consumed; safe to overwrite next iter

        tile = nxt;
        par ^= 1;
    }
}

// ---------------- Aggregate (gather) + bias + PReLU ----------------

__global__ __launch_bounds__(256) void k_agg(
    const int* __restrict__ row_ptr, const int2* __restrict__ csr,
    const unsigned int* __restrict__ Tadj, const unsigned int* __restrict__ Tdiff,
    const float* __restrict__ b1, const float* __restrict__ a1,
    const float* __restrict__ b2, const float* __restrict__ a2,
    float* __restrict__ out) {

    int wid  = threadIdx.x >> 6;
    int lane = threadIdx.x & 63;
    int node = blockIdx.x * 4 + wid;
    int g    = blockIdx.y;

    const int* rp = row_ptr + g * (N_NODES + 1);
    const int2* el = csr + (size_t)g * N_EDGES;
    const unsigned int* Tu = g ? Tdiff : Tadj;

    int e  = rp[node];
    int e1 = rp[node + 1];
    float ax = 0.f, ay = 0.f;

    for (; e + 4 <= e1; e += 4) {
        int2 m0 = el[e + 0], m1 = el[e + 1], m2 = el[e + 2], m3 = el[e + 3];
        unsigned int q0 = Tu[(size_t)m0.x * 64 + lane];
        unsigned int q1 = Tu[(size_t)m1.x * 64 + lane];
        unsigned int q2 = Tu[(size_t)m2.x * 64 + lane];
        unsigned int q3 = Tu[(size_t)m3.x * 64 + lane];
        float w0 = __int_as_float(m0.y), w1 = __int_as_float(m1.y);
        float w2 = __int_as_float(m2.y), w3 = __int_as_float(m3.y);
        ax += w0 * bflo(q0); ay += w0 * bfhi(q0);
        ax += w1 * bflo(q1); ay += w1 * bfhi(q1);
        ax += w2 * bflo(q2); ay += w2 * bfhi(q2);
        ax += w3 * bflo(q3); ay += w3 * bfhi(q3);
    }
    for (; e < e1; ++e) {
        int2 m = el[e];
        unsigned int q = Tu[(size_t)m.x * 64 + lane];
        float w = __int_as_float(m.y);
        ax += w * bflo(q); ay += w * bfhi(q);
    }

    const float* bias = g ? b2 : b1;
    float slope = g ? a2[0] : a1[0];
    int f = 2 * lane;
    size_t base;
    int fo;
    if (lane < 32) { base = g ? (size_t)3200000 : (size_t)0;       fo = f; }
    else           { base = g ? (size_t)9600000 : (size_t)6400000; fo = f - 64; }
    float v0 = ax + bias[fo];
    float v1 = ay + bias[fo + 1];
    v0 = (v0 >= 0.f) ? v0 : slope * v0;
    v1 = (v1 >= 0.f) ? v1 : slope * v1;
    float2 res; res.x = v0; res.y = v1;
    *reinterpret_cast<float2*>(out + base + (size_t)node * 64 + fo) = res;
}

// ---------------- launch ----------------

extern "C" void kernel_launch(void* const* d_in, const int* in_sizes, int n_in,
                              void* d_out, int out_size, void* d_ws, size_t ws_size,
                              hipStream_t stream) {
    const float* bf_      = (const float*)d_in[0];
    const float* bl_      = (const float*)d_in[1];
    const float* shuf_fts = (const float*)d_in[2];
    const float* shuf_fls = (const float*)d_in[3];
    const int*   adj_rows = (const int*)d_in[4];
    const int*   adj_cols = (const int*)d_in[5];
    const float* adj_w    = (const float*)d_in[6];
    const int*   diff_rows= (const int*)d_in[7];
    const int*   diff_cols= (const int*)d_in[8];
    const float* diff_w   = (const float*)d_in[9];
    const float* W1       = (const float*)d_in[10];
    const float* b1       = (const float*)d_in[11];
    const float* a1       = (const float*)d_in[12];
    const float* W2       = (const float*)d_in[13];
    const float* b2       = (const float*)d_in[14];
    const float* a2       = (const float*)d_in[15];
    float* out = (float*)d_out;

    char* ws = (char*)d_ws;
    unsigned short* Tadj  = (unsigned short*)(ws);                         // 12.8 MB
    unsigned short* Tdiff = (unsigned short*)(ws + 12800000);              // 12.8 MB
    int2* csr             = (int2*)(ws + 25600000);                        // 12.8 MB
    int*  row_ptr         = (int*)(ws + 38400000);                         // 400 KB
    int*  gcnt            = (int*)(ws + 38801024);                         // 250 ints
    unsigned short* WTg   = (unsigned short*)(ws + 38803072);              // 65536 B

    // bin buckets live in d_out (16.4 MB <= 51.2 MB), dead before k_agg writes output
    int2* bin = (int2*)d_out;

    hipMemsetAsync(gcnt, 0, 2 * NB * sizeof(int), stream);

    k_bin<<<dim3((N_EDGES + BIN_BLK - 1) / BIN_BLK, 2), dim3(256), 0, stream>>>(
        adj_rows, adj_cols, adj_w, diff_rows, diff_cols, diff_w, gcnt, bin);
    k_wt<<<dim3(2), dim3(256), 0, stream>>>(W1, W2, WTg);
    k_build<<<dim3(NB, 2), dim3(256), 0, stream>>>(gcnt, bin, csr, row_ptr);

    k_gemm<<<dim3(GEMMX, 4), dim3(256), 0, stream>>>(
        bf_, bl_, shuf_fts, shuf_fls, WTg, Tadj, Tdiff);

    k_agg<<<dim3(N_NODES / 4, 2), dim3(256), 0, stream>>>(
        row_ptr, csr, (const unsigned int*)Tadj, (const unsigned int*)Tdiff,
        b1, a1, b2, a2, out);
}

// Round 12
// 197.042 us; speedup vs baseline: 1.0754x; 1.0754x over previous
//
#include <hip/hip_runtime.h>
#include <hip/hip_bf16.h>

#define N_NODES 50000
#define N_EDGES 800000
#define N_IN    256
#define N_H     64
#define NB      125    // buckets per graph
#define RPB     400    // rows per bucket (NB*RPB == N_NODES)
#define BCAP    8192   // bucket capacity (mean 6400)
#define EPT     8      // edges per thread in bin path
#define BIN_BLK 2048   // edges per bin block
#define BIN_GRID 391   // ceil(N_EDGES / BIN_BLK)
#define GSTRIDE 256    // u16 per WTg row
#define ASTRIDE 264    // u16 per A-LDS row (256 + 8 pad)
#define NTILES  1563   // ceil(N_NODES/32)
#define GEMMX   192    // persistent gemm blocks per stream (x4 streams = 768)

typedef short short8 __attribute__((ext_vector_type(8)));
typedef float f32x4  __attribute__((ext_vector_type(4)));

__device__ inline short f2bf(float f) {
    __bf16 h = (__bf16)f;
    return (short)__builtin_bit_cast(unsigned short, h);
}
__device__ inline float bflo(unsigned int q) { return __uint_as_float(q << 16); }
__device__ inline float bfhi(unsigned int q) { return __uint_as_float(q & 0xFFFF0000u); }

// ---------------- prep: bf16 W^T tables in global ----------------

__global__ __launch_bounds__(256) void k_wt(const float* __restrict__ W1,
                                            const float* __restrict__ W2,
                                            unsigned short* __restrict__ WTg) {
    int g = blockIdx.x;
    const float* W = g ? W2 : W1;
    unsigned short* o = WTg + (size_t)g * 64 * GSTRIDE;
    for (int i = threadIdx.x; i < N_IN * N_H; i += 256) {
        int k = i >> 6, c = i & 63;
        o[c * GSTRIDE + k] = (unsigned short)f2bf(W[i]);
    }
}

// ---------------- fused: bin blocks (first 782) + persistent gemm blocks (768) ----------------

__global__ __launch_bounds__(256, 3) void k_fused(
    // bin inputs
    const int* __restrict__ adj_rows, const int* __restrict__ adj_cols,
    const float* __restrict__ adj_w,
    const int* __restrict__ diff_rows, const int* __restrict__ diff_cols,
    const float* __restrict__ diff_w,
    int* __restrict__ gcnt, int2* __restrict__ bin,
    // gemm inputs
    const float* __restrict__ X0, const float* __restrict__ X1,
    const float* __restrict__ X2, const float* __restrict__ X3,
    const unsigned short* __restrict__ WTg,
    unsigned short* __restrict__ Tadj, unsigned short* __restrict__ Tdiff) {

    __shared__ __align__(16) unsigned short A[32 * ASTRIDE];   // 16896 B (bin path reuses)

    int fid = blockIdx.x;
    int t = threadIdx.x;

    if (fid < 2 * BIN_GRID) {
        // ================= bin path =================
        int g = (fid >= BIN_GRID);
        int bx = g ? (fid - BIN_GRID) : fid;
        const int*   rows = g ? diff_rows : adj_rows;
        const int*   cols = g ? diff_cols : adj_cols;
        const float* ww   = g ? diff_w    : adj_w;
        int base_e = bx * BIN_BLK;

        int* lcnt  = (int*)A;          // [NB]
        int* lbase = ((int*)A) + NB;   // [NB]
        for (int i = t; i < NB; i += 256) lcnt[i] = 0;
        __syncthreads();

        int lpos[EPT];
        int bkt[EPT];
        #pragma unroll
        for (int e = 0; e < EPT; ++e) {
            int idx = base_e + e * 256 + t;
            if (idx < N_EDGES) {
                int r = rows[idx];
                int b = r / RPB;
                bkt[e] = b;
                lpos[e] = atomicAdd(&lcnt[b], 1);
            } else bkt[e] = -1;
        }
        __syncthreads();
        for (int i = t; i < NB; i += 256) lbase[i] = atomicAdd(&gcnt[g * NB + i], lcnt[i]);
        __syncthreads();

        #pragma unroll
        for (int e = 0; e < EPT; ++e) {
            int idx = base_e + e * 256 + t;
            if (idx < N_EDGES) {
                unsigned int r = (unsigned int)rows[idx];
                unsigned int c = (unsigned int)cols[idx];
                int b = bkt[e];
                int2 m;
                m.x = (int)((r << 16) | c);
                m.y = __float_as_int(ww[idx]);
                bin[((size_t)(g * NB + b)) * BCAP + lbase[b] + lpos[e]] = m;
            }
        }
        return;
    }

    // ================= gemm path (r10 internals) =================
    int gid = fid - 2 * BIN_GRID;      // 0..767
    int gy = gid & 3;
    int g = gy >> 1, s = gy & 1;
    const float* X = g ? (s ? X3 : X1) : (s ? X2 : X0);
    unsigned short* T = g ? Tdiff : Tadj;
    const unsigned short* WB = WTg + (size_t)g * 64 * GSTRIDE;
    int coloff = s * 64;

    int wid  = t >> 6;
    int lane = t & 63;
    int l15  = lane & 15;
    int kg   = lane >> 4;
    int col4 = t & 63;

    // B fragments once per block (L2-hot 32 KB table)
    int ctbase = (wid >> 1) * 2;
    short8 bfr[2][8];
    #pragma unroll
    for (int c2 = 0; c2 < 2; ++c2) {
        int ct = ctbase + c2;
        #pragma unroll
        for (int kt = 0; kt < 8; ++kt) {
            bfr[c2][kt] = *reinterpret_cast<const short8*>(
                WB + ((ct * 16 + l15) * GSTRIDE + kt * 32 + kg * 8));
        }
    }

    int rt = wid & 1;
    int tile = gid >> 2;               // 0..191

    float4 v[8], v2[8];
    {
        int base = tile * 32 + wid;
        #pragma unroll
        for (int j = 0; j < 8; ++j) {
            int grow = base + 4 * j; if (grow >= N_NODES) grow = N_NODES - 1;
            v[j] = ((const float4*)(X + (size_t)grow * N_IN))[col4];
        }
    }

    while (tile < NTILES) {
        int nxt = tile + GEMMX;
        if (nxt < NTILES) {
            int base = nxt * 32 + wid;
            #pragma unroll
            for (int j = 0; j < 8; ++j) {
                int grow = base + 4 * j; if (grow >= N_NODES) grow = N_NODES - 1;
                v2[j] = ((const float4*)(X + (size_t)grow * N_IN))[col4];
            }
        }
        __builtin_amdgcn_sched_barrier(0);

        #pragma unroll
        for (int j = 0; j < 8; ++j) {
            int row = wid + 4 * j;
            ushort4 c;
            c.x = (unsigned short)f2bf(v[j].x);
            c.y = (unsigned short)f2bf(v[j].y);
            c.z = (unsigned short)f2bf(v[j].z);
            c.w = (unsigned short)f2bf(v[j].w);
            *reinterpret_cast<ushort4*>(&A[row * ASTRIDE + col4 * 4]) = c;
        }
        __syncthreads();

        f32x4 acc[2];
        acc[0] = (f32x4){0.f, 0.f, 0.f, 0.f};
        acc[1] = (f32x4){0.f, 0.f, 0.f, 0.f};
        #pragma unroll
        for (int kt = 0; kt < 8; ++kt) {
            short8 af = *reinterpret_cast<const short8*>(
                &A[(rt * 16 + l15) * ASTRIDE + kt * 32 + kg * 8]);
            acc[0] = __builtin_amdgcn_mfma_f32_16x16x32_bf16(af, bfr[0][kt], acc[0], 0, 0, 0);
            acc[1] = __builtin_amdgcn_mfma_f32_16x16x32_bf16(af, bfr[1][kt], acc[1], 0, 0, 0);
        }

        int rb0 = tile * 32;
        #pragma unroll
        for (int c2 = 0; c2 < 2; ++c2) {
            int col = coloff + (ctbase + c2) * 16 + l15;
            #pragma unroll
            for (int r = 0; r < 4; ++r) {
                int row = rb0 + rt * 16 + kg * 4 + r;
                if (row < N_NODES)
                    T[(size_t)row * 128 + col] = (unsigned short)f2bf(acc[c2][r]);
            }
        }
        __syncthreads();

        tile = nxt;
        #pragma unroll
        for (int j = 0; j < 8; ++j) v[j] = v2[j];
    }
}

// ---------------- per-bucket CSR build (parallel sbase) ----------------

__global__ __launch_bounds__(256) void k_build(
    const int* __restrict__ gcnt, const int2* __restrict__ bin,
    int2* __restrict__ csr, int* __restrict__ row_ptr) {

    int g = blockIdx.y, b = blockIdx.x, t = threadIdx.x;
    __shared__ int hist[512];
    __shared__ int s2[256];
    __shared__ int sbase;

    for (int i = t; i < 512; i += 256) hist[i] = 0;
    __syncthreads();

    int cnt = gcnt[g * NB + b];
    const int2* be = bin + ((size_t)(g * NB + b)) * BCAP;
    int r0 = b * RPB;

    for (int i = t; i < cnt; i += 256) {
        unsigned int rc = (unsigned int)be[i].x;
        atomicAdd(&hist[(rc >> 16) - r0], 1);
    }

    // parallel sbase: sum of gcnt[g*NB + 0..b-1]
    s2[t] = (t < b) ? gcnt[g * NB + t] : 0;   // b < NB = 125 < 256
    __syncthreads();
    for (int off = 128; off > 0; off >>= 1) {
        if (t < off) s2[t] += s2[t + off];
        __syncthreads();
    }
    if (t == 0) sbase = s2[0];
    __syncthreads();

    int v0 = hist[2 * t], v1 = hist[2 * t + 1];
    int local = v0 + v1;
    s2[t] = local;
    __syncthreads();
    for (int off = 1; off < 256; off <<= 1) {
        int v = (t >= off) ? s2[t - off] : 0;
        __syncthreads();
        s2[t] += v;
        __syncthreads();
    }
    int e0 = sbase + (s2[t] - local);
    int e1 = e0 + v0;

    int* rp = row_ptr + g * (N_NODES + 1);
    if (2 * t < RPB)     rp[r0 + 2 * t]     = e0;
    if (2 * t + 1 < RPB) rp[r0 + 2 * t + 1] = e1;
    __syncthreads();
    hist[2 * t] = e0;
    hist[2 * t + 1] = e1;
    __syncthreads();

    int2* cg = csr + (size_t)g * N_EDGES;
    for (int i = t; i < cnt; i += 256) {
        int2 m = be[i];
        unsigned int rc = (unsigned int)m.x;
        int lr = (int)(rc >> 16) - r0;
        int pos = atomicAdd(&hist[lr], 1);
        int2 o;
        o.x = (int)(rc & 0xFFFFu);
        o.y = m.y;
        cg[pos] = o;
    }
    if (b == NB - 1 && t == 0) rp[N_NODES] = N_EDGES;
}

// ---------------- Aggregate (gather) + bias + PReLU  [at roofline, unchanged] ----------------

__global__ __launch_bounds__(256) void k_agg(
    const int* __restrict__ row_ptr, const int2* __restrict__ csr,
    const unsigned int* __restrict__ Tadj, const unsigned int* __restrict__ Tdiff,
    const float* __restrict__ b1, const float* __restrict__ a1,
    const float* __restrict__ b2, const float* __restrict__ a2,
    float* __restrict__ out) {

    int wid  = threadIdx.x >> 6;
    int lane = threadIdx.x & 63;
    int node = blockIdx.x * 4 + wid;
    int g    = blockIdx.y;

    const int* rp = row_ptr + g * (N_NODES + 1);
    const int2* el = csr + (size_t)g * N_EDGES;
    const unsigned int* Tu = g ? Tdiff : Tadj;

    int e  = rp[node];
    int e1 = rp[node + 1];
    float ax = 0.f, ay = 0.f;

    for (; e + 4 <= e1; e += 4) {
        int2 m0 = el[e + 0], m1 = el[e + 1], m2 = el[e + 2], m3 = el[e + 3];
        unsigned int q0 = Tu[(size_t)m0.x * 64 + lane];
        unsigned int q1 = Tu[(size_t)m1.x * 64 + lane];
        unsigned int q2 = Tu[(size_t)m2.x * 64 + lane];
        unsigned int q3 = Tu[(size_t)m3.x * 64 + lane];
        float w0 = __int_as_float(m0.y), w1 = __int_as_float(m1.y);
        float w2 = __int_as_float(m2.y), w3 = __int_as_float(m3.y);
        ax += w0 * bflo(q0); ay += w0 * bfhi(q0);
        ax += w1 * bflo(q1); ay += w1 * bfhi(q1);
        ax += w2 * bflo(q2); ay += w2 * bfhi(q2);
        ax += w3 * bflo(q3); ay += w3 * bfhi(q3);
    }
    for (; e < e1; ++e) {
        int2 m = el[e];
        unsigned int q = Tu[(size_t)m.x * 64 + lane];
        float w = __int_as_float(m.y);
        ax += w * bflo(q); ay += w * bfhi(q);
    }

    const float* bias = g ? b2 : b1;
    float slope = g ? a2[0] : a1[0];
    int f = 2 * lane;
    size_t base;
    int fo;
    if (lane < 32) { base = g ? (size_t)3200000 : (size_t)0;       fo = f; }
    else           { base = g ? (size_t)9600000 : (size_t)6400000; fo = f - 64; }
    float v0 = ax + bias[fo];
    float v1 = ay + bias[fo + 1];
    v0 = (v0 >= 0.f) ? v0 : slope * v0;
    v1 = (v1 >= 0.f) ? v1 : slope * v1;
    float2 res; res.x = v0; res.y = v1;
    *reinterpret_cast<float2*>(out + base + (size_t)node * 64 + fo) = res;
}

// ---------------- launch ----------------

extern "C" void kernel_launch(void* const* d_in, const int* in_sizes, int n_in,
                              void* d_out, int out_size, void* d_ws, size_t ws_size,
                              hipStream_t stream) {
    const float* bf_      = (const float*)d_in[0];
    const float* bl_      = (const float*)d_in[1];
    const float* shuf_fts = (const float*)d_in[2];
    const float* shuf_fls = (const float*)d_in[3];
    const int*   adj_rows = (const int*)d_in[4];
    const int*   adj_cols = (const int*)d_in[5];
    const float* adj_w    = (const float*)d_in[6];
    const int*   diff_rows= (const int*)d_in[7];
    const int*   diff_cols= (const int*)d_in[8];
    const float* diff_w   = (const float*)d_in[9];
    const float* W1       = (const float*)d_in[10];
    const float* b1       = (const float*)d_in[11];
    const float* a1       = (const float*)d_in[12];
    const float* W2       = (const float*)d_in[13];
    const float* b2       = (const float*)d_in[14];
    const float* a2       = (const float*)d_in[15];
    float* out = (float*)d_out;

    char* ws = (char*)d_ws;
    unsigned short* Tadj  = (unsigned short*)(ws);                         // 12.8 MB
    unsigned short* Tdiff = (unsigned short*)(ws + 12800000);              // 12.8 MB
    int2* csr             = (int2*)(ws + 25600000);                        // 12.8 MB
    int*  row_ptr         = (int*)(ws + 38400000);                         // 400 KB
    int*  gcnt            = (int*)(ws + 38801024);                         // 250 ints
    unsigned short* WTg   = (unsigned short*)(ws + 38803072);              // 65536 B

    // bin buckets live in d_out (16.4 MB <= 51.2 MB), consumed by k_build before k_agg writes
    int2* bin = (int2*)d_out;

    hipMemsetAsync(gcnt, 0, 2 * NB * sizeof(int), stream);

    k_wt<<<dim3(2), dim3(256), 0, stream>>>(W1, W2, WTg);

    k_fused<<<dim3(2 * BIN_GRID + 4 * GEMMX), dim3(256), 0, stream>>>(
        adj_rows, adj_cols, adj_w, diff_rows, diff_cols, diff_w, gcnt, bin,
        bf_, bl_, shuf_fts, shuf_fls, WTg, Tadj, Tdiff);

    k_build<<<dim3(NB, 2), dim3(256), 0, stream>>>(gcnt, bin, csr, row_ptr);

    k_agg<<<dim3(N_NODES / 4, 2), dim3(256), 0, stream>>>(
        row_ptr, csr, (const unsigned int*)Tadj, (const unsigned int*)Tdiff,
        b1, a1, b2, a2, out);
}